// Round 8
// baseline (278.825 us; speedup 1.0000x reference)
//
#include <hip/hip_runtime.h>
#include <hip/hip_bf16.h>

// ---- problem constants ----
#define B_TOT   4096
#define T_LEN   200
#define F_IN    76
#define H_DIM   128
#define S_DIM   17
#define BLK_B   16
#define NTHREADS 512
#define NT_CHUNK 4
#define NCHUNK  (T_LEN / NT_CHUNK)      // 50
#define XPITCH  104                     // shorts
#define HPITCH  136                     // shorts
#define XHALF   (NT_CHUNK * BLK_B * XPITCH)  // shorts per x double-buffer half
#define PF_N    5

static_assert(NCHUNK * NT_CHUNK == T_LEN, "chunking must cover T exactly");

using f32x4 = __attribute__((ext_vector_type(4))) float;
using s16x8 = __attribute__((ext_vector_type(8))) short;

#if __has_builtin(__builtin_amdgcn_exp2f)
#define EXP2(v) __builtin_amdgcn_exp2f(v)
#else
#define EXP2(v) exp2f(v)
#endif
#if __has_builtin(__builtin_amdgcn_rcpf)
#define RCP(v) __builtin_amdgcn_rcpf(v)
#else
#define RCP(v) (1.0f / (v))
#endif

__device__ __forceinline__ short f2bf(float f) {
    union { float f; unsigned u; } v; v.f = f;
    unsigned r = v.u + 0x7FFFu + ((v.u >> 16) & 1u);   // RNE
    return (short)(r >> 16);
}
__device__ __forceinline__ float bf2f(short s) {
    union { unsigned u; float f; } v;
    v.u = ((unsigned)(unsigned short)s) << 16;
    return v.f;
}
__device__ __forceinline__ unsigned cvt_pk_bf16(float lo, float hi) {
    unsigned r;
    asm("v_cvt_pk_bf16_f32 %0, %1, %2" : "=v"(r) : "v"(lo), "v"(hi));
    return r;
}
__device__ __forceinline__ f32x4 mfma16x32(s16x8 a, s16x8 b, f32x4 c) {
    return __builtin_amdgcn_mfma_f32_16x16x32_bf16(a, b, c, 0, 0, 0);
}

// LDS-only barrier: do NOT drain vmcnt (keeps global prefetch in flight).
#define LDS_BARRIER() asm volatile("s_waitcnt lgkmcnt(0)\n\ts_barrier" ::: "memory")

// Nonlinearity for 4 rows of one 16-col group. Gates pre-scaled by -log2e
// (g gate by -2log2e), so sigmoid(x)=1/(1+exp2(arg)), tanh via exp2.
#define NONLIN4(G0, G1, G2, G3, CR, HV)                                 \
    _Pragma("unroll")                                                   \
    for (int r = 0; r < 4; ++r) {                                       \
        float A  = EXP2((G0)[r]);                                       \
        float Bv = EXP2((G1)[r]);                                       \
        float E  = EXP2((G2)[r]);                                       \
        float Dv = EXP2((G3)[r]);                                       \
        float p1 = 1.f + A, p2 = 1.f + Bv, p3 = 1.f + E;                \
        float q13 = p1 * p3;                                            \
        float num = fmaf((CR)[r], q13, (1.f - E) * p2);                 \
        float cn  = num * RCP(q13 * p2);                                \
        (CR)[r] = cn;                                                   \
        float Ec = EXP2(fminf(cn * (-2.f * C1), 80.f));                 \
        (HV)[r] = (1.f - Ec) * RCP((1.f + Dv) * (1.f + Ec));            \
    }

__global__ __launch_bounds__(NTHREADS, 2) void lstm_fused(
    const float* __restrict__ x,    const float* __restrict__ stat,
    const float* __restrict__ h0,   const float* __restrict__ c0,
    const float* __restrict__ W_ih, const float* __restrict__ W_hh,
    const float* __restrict__ b_ih, const float* __restrict__ b_hh,
    const float* __restrict__ W_lin, const float* __restrict__ b_lin,
    float* __restrict__ out)
{
    // LDS budget: 26624 + 4352 + 16384 + 16384 + 98304 = 162048 B (<160 KiB)
    __shared__ __align__(16) short xbuf[2 * XHALF];               // x chunks (dbuf)
    __shared__ __align__(16) short hbuf[BLK_B * HPITCH];          // h (single buf)
    __shared__ __align__(16) f32x4 gbuf[4 * 4 * 64];              // B-wave gate acc
    __shared__ __align__(16) f32x4 xabuf[4 * 4 * 64];             // xa for A-waves
    __shared__ __align__(16) s16x8 wihbuf[4 * 4 * 2 * 3 * 64];    // W_ih frags

    const int tid  = threadIdx.x;
    const int lane = tid & 63;
    const int w    = tid >> 6;
    const int p    = w & 3;            // pair index (A_p <-> B_p)
    const bool isB = w >= 4;           // waves 0-3 = A (nonlin), 4-7 = B (xproj)
    const int lrow = lane & 15;        // MFMA A-operand row / B-operand col
    const int lk8  = (lane >> 4) << 3; // k sub-base within a 32-wide K tile
    const int r0   = (lane >> 4) << 2; // C/D batch-row base
    const int b0   = blockIdx.x * BLK_B;
    const int hbA  = p * 16;           // A-wave's hidden cols
    const int hbB  = 64 + p * 16;      // B-wave's hidden cols
    const int hbOwn = isB ? hbB : hbA;

    const float C1 = 1.44269504088896f;  // log2(e)
    const float gs[4] = { -C1, -C1, -2.0f * C1, -C1 }; // i,f,g,o pre-scales

    // ---- every wave: own W_hh fragments in registers (scale folded) ----
    s16x8 whh[4][4];
#pragma unroll
    for (int nt = 0; nt < 4; ++nt) {
        const int col = nt * H_DIM + hbOwn + lrow;
        const float s = gs[nt];
#pragma unroll
        for (int kt = 0; kt < 4; ++kt) {
            s16x8 f;
#pragma unroll
            for (int j = 0; j < 8; ++j)
                f[j] = f2bf(W_hh[col * H_DIM + kt * 32 + lk8 + j] * s);
            whh[nt][kt] = f;
        }
    }

    // ---- B waves: W_ih fragments -> LDS, bias folded at k=76,77 (x pad = 1) ----
    if (isB) {
#pragma unroll
        for (int nt = 0; nt < 4; ++nt) {
#pragma unroll
            for (int cg = 0; cg < 2; ++cg) {
                const int col = nt * H_DIM + (cg ? hbB : hbA) + lrow;
                const float s = gs[nt];
                const float bsc = (b_ih[col] + b_hh[col]) * s;
                const short bhi = f2bf(bsc);
                const short blo = f2bf(bsc - bf2f(bhi));  // 2-term bf16 bias
#pragma unroll
                for (int kt = 0; kt < 3; ++kt) {
                    s16x8 f;
#pragma unroll
                    for (int j = 0; j < 8; ++j) {
                        const int k = kt * 32 + lk8 + j;
                        short v;
                        if (k < F_IN)     v = f2bf(W_ih[col * F_IN + k] * s);
                        else if (k == 76) v = bhi;
                        else if (k == 77) v = blo;
                        else              v = 0;
                        f[j] = v;
                    }
                    wihbuf[(((p * 4 + nt) * 2 + cg) * 3 + kt) * 64 + lane] = f;
                }
            }
        }
    }

    // ---- A waves: c-state, hbuf init, xbuf pad init, staging setup ----
    float c0r[4], c1r[4];
    int ldsoff[PF_N];
    const float* psrc = x;
    const int pidx_m = tid & 15;
    if (!isB) {
#pragma unroll
        for (int r = 0; r < 4; ++r) {
            c0r[r] = c0[(b0 + r0 + r) * H_DIM + hbA + lrow];
            c1r[r] = c0[(b0 + r0 + r) * H_DIM + hbB + lrow];
        }
        for (int i = tid; i < BLK_B * H_DIM; i += 256) {
            int row = i >> 7, cc = i & 127;
            hbuf[row * HPITCH + cc] = f2bf(h0[(b0 + row) * H_DIM + cc]);
        }
        // pad cols [76,104): 1.0 at 76 and 77 (bias carriers), 0 elsewhere
        for (int i = tid; i < 2 * NT_CHUNK * BLK_B * (XPITCH - F_IN); i += 256) {
            int f  = i % (XPITCH - F_IN);
            int rs = i / (XPITCH - F_IN);
            xbuf[rs * XPITCH + F_IN + f] = (f < 2) ? (short)0x3F80 : (short)0;
        }
        const int prow = tid >> 4;
        psrc = x + (size_t)(b0 + prow) * (T_LEN * F_IN) + pidx_m * 4;
#pragma unroll
        for (int i = 0; i < PF_N; ++i) {
            int s4 = pidx_m + 16 * i, q = 4 * s4;
            int tp = (q * 863) >> 16;          // == q / 76 for q < 608
            int f0 = q - 76 * tp;
            ldsoff[i] = (tp * BLK_B + prow) * XPITCH + f0;
        }
    }

    f32x4 pf[PF_N];
    auto issue = [&](int ch) {
        const float* pp = psrc + (size_t)ch * (NT_CHUNK * F_IN);
#pragma unroll
        for (int i = 0; i < PF_N; ++i)
            if (i < PF_N - 1 || pidx_m < 12)
                pf[i] = *(const f32x4*)(pp + i * 64);
    };
    auto commit = [&](int half) {
        short* xb0 = xbuf + half * XHALF;
#pragma unroll
        for (int i = 0; i < PF_N; ++i)
            if (i < PF_N - 1 || pidx_m < 12) {
                unsigned lo = cvt_pk_bf16(pf[i].x, pf[i].y);
                unsigned hi = cvt_pk_bf16(pf[i].z, pf[i].w);
                unsigned long long v = ((unsigned long long)hi << 32) | lo;
                *(unsigned long long*)(xb0 + ldsoff[i]) = v;  // 8B aligned
            }
    };

    if (!isB) { issue(0); commit(0); }
    __syncthreads();

    // ---- B: x-projection machinery ----
    s16x8 axr[3];
    f32x4 xaB[4];
    auto load_axr = [&](int half, int slot) {
#pragma unroll
        for (int kt = 0; kt < 3; ++kt)
            axr[kt] = *(const s16x8*)&xbuf[half * XHALF
                        + (slot * BLK_B + lrow) * XPITCH + kt * 32 + lk8];
    };
    auto do_xproj = [&]() {
        const f32x4 z = { 0.f, 0.f, 0.f, 0.f };
#pragma unroll
        for (int nt = 0; nt < 4; ++nt) {            // partner A's tiles -> LDS
            const int base = ((p * 4 + nt) * 2 + 0) * 3;
            f32x4 t = mfma16x32(axr[0], wihbuf[(base + 0) * 64 + lane], z);
            t = mfma16x32(axr[1], wihbuf[(base + 1) * 64 + lane], t);
            t = mfma16x32(axr[2], wihbuf[(base + 2) * 64 + lane], t);
            xabuf[(p * 4 + nt) * 64 + lane] = t;
        }
#pragma unroll
        for (int nt = 0; nt < 4; ++nt) {            // own tiles -> regs
            const int base = ((p * 4 + nt) * 2 + 1) * 3;
            f32x4 t = mfma16x32(axr[0], wihbuf[(base + 0) * 64 + lane], z);
            t = mfma16x32(axr[1], wihbuf[(base + 1) * 64 + lane], t);
            t = mfma16x32(axr[2], wihbuf[(base + 2) * 64 + lane], t);
            xaB[nt] = t;
        }
    };

    if (isB) { load_axr(0, 0); do_xproj(); }   // xa(0)
    LDS_BARRIER();

#pragma unroll 1
    for (int ch = 0; ch < NCHUNK; ++ch) {
        const int xc = ch & 1;
#pragma unroll 1
        for (int tt = 0; tt < NT_CHUNK; ++tt) {
            // ---------- phase 1: h-GEMM (all waves), B publishes gates ----------
            s16x8 ah[4];
#pragma unroll
            for (int kt = 0; kt < 4; ++kt)
                ah[kt] = *(const s16x8*)&hbuf[lrow * HPITCH + kt * 32 + lk8];
            f32x4 acc[4];
            if (!isB) {
#pragma unroll
                for (int nt = 0; nt < 4; ++nt) {
                    f32x4 t = xabuf[(p * 4 + nt) * 64 + lane];  // C-in = xa(t)
                    t = mfma16x32(ah[0], whh[nt][0], t);
                    t = mfma16x32(ah[1], whh[nt][1], t);
                    t = mfma16x32(ah[2], whh[nt][2], t);
                    t = mfma16x32(ah[3], whh[nt][3], t);
                    acc[nt] = t;
                }
            } else {
#pragma unroll
                for (int nt = 0; nt < 4; ++nt) {
                    f32x4 t = xaB[nt];
                    t = mfma16x32(ah[0], whh[nt][0], t);
                    t = mfma16x32(ah[1], whh[nt][1], t);
                    t = mfma16x32(ah[2], whh[nt][2], t);
                    t = mfma16x32(ah[3], whh[nt][3], t);
                    acc[nt] = t;
                }
#pragma unroll
                for (int nt = 0; nt < 4; ++nt)
                    gbuf[(p * 4 + nt) * 64 + lane] = acc[nt];   // gates -> A
                const int ttn = (tt + 1) & (NT_CHUNK - 1);       // x frags for t+1
                const int xcn = (tt == NT_CHUNK - 1) ? (xc ^ 1) : xc;
                load_axr(xcn, ttn);
            }
            LDS_BARRIER();
            // ---------- phase 2: A nonlin (VALU)  ||  B xproj(t+1) (MFMA) ------
            if (!isB) {
                if (tt == 0 && ch + 1 < NCHUNK) issue(ch + 1);
                f32x4 gB[4];
#pragma unroll
                for (int nt = 0; nt < 4; ++nt)
                    gB[nt] = gbuf[(p * 4 + nt) * 64 + lane];
                float hv0[4], hv1[4];
                NONLIN4(acc[0], acc[1], acc[2], acc[3], c0r, hv0);  // own cols
                NONLIN4(gB[0],  gB[1],  gB[2],  gB[3],  c1r, hv1);  // partner cols
                unsigned u01 = cvt_pk_bf16(hv0[0], hv0[1]);
                unsigned u23 = cvt_pk_bf16(hv0[2], hv0[3]);
                unsigned v01 = cvt_pk_bf16(hv1[0], hv1[1]);
                unsigned v23 = cvt_pk_bf16(hv1[2], hv1[3]);
                unsigned short* hp0 = (unsigned short*)&hbuf[r0 * HPITCH + hbA + lrow];
                hp0[0 * HPITCH] = (unsigned short)u01;
                hp0[1 * HPITCH] = (unsigned short)(u01 >> 16);
                hp0[2 * HPITCH] = (unsigned short)u23;
                hp0[3 * HPITCH] = (unsigned short)(u23 >> 16);
                unsigned short* hp1 = (unsigned short*)&hbuf[r0 * HPITCH + hbB + lrow];
                hp1[0 * HPITCH] = (unsigned short)v01;
                hp1[1 * HPITCH] = (unsigned short)(v01 >> 16);
                hp1[2 * HPITCH] = (unsigned short)v23;
                hp1[3 * HPITCH] = (unsigned short)(v23 >> 16);
                if (tt == 2 && ch + 1 < NCHUNK) commit(xc ^ 1);
            } else {
                if (ch * NT_CHUNK + tt < T_LEN - 1) do_xproj();   // xa(t+1)
            }
            LDS_BARRIER();
        }
    }

    // ---- final linear head: out[b] = [h, static] . W_lin + b_lin ----
    if (tid < BLK_B) {
        const int row = tid;
        float a = b_lin[0];
        for (int k = 0; k < H_DIM; ++k)
            a += bf2f(hbuf[row * HPITCH + k]) * W_lin[k];
        for (int s = 0; s < S_DIM; ++s)
            a += stat[(b0 + row) * S_DIM + s] * W_lin[H_DIM + s];
        out[b0 + row] = a;
    }
}

extern "C" void kernel_launch(void* const* d_in, const int* in_sizes, int n_in,
                              void* d_out, int out_size, void* d_ws, size_t ws_size,
                              hipStream_t stream) {
    const float* xx   = (const float*)d_in[0];
    const float* st   = (const float*)d_in[1];
    const float* h0   = (const float*)d_in[2];
    const float* c0   = (const float*)d_in[3];
    const float* Wih  = (const float*)d_in[4];
    const float* Whh  = (const float*)d_in[5];
    const float* bih  = (const float*)d_in[6];
    const float* bhh  = (const float*)d_in[7];
    const float* Wlin = (const float*)d_in[8];
    const float* blin = (const float*)d_in[9];
    float* o = (float*)d_out;

    lstm_fused<<<B_TOT / BLK_B, NTHREADS, 0, stream>>>(
        xx, st, h0, c0, Wih, Whh, bih, bhh, Wlin, blin, o);
}

// Round 9
// 219.617 us; speedup vs baseline: 1.2696x; 1.2696x over previous
//
#include <hip/hip_runtime.h>
#include <hip/hip_bf16.h>

// ---- problem constants ----
#define B_TOT   4096
#define T_LEN   200
#define F_IN    76
#define H_DIM   128
#define S_DIM   17
#define BLK_B   16
#define NTHREADS 512
#define NT_CHUNK 8
#define NCHUNK  (T_LEN / NT_CHUNK)      // 25
#define XPITCH  104                     // shorts
#define HPITCH  136                     // shorts
#define ROW_F4  ((NT_CHUNK * F_IN) / 4) // 152 float4 per row per chunk
#define PF_N    5

static_assert(NCHUNK * NT_CHUNK == T_LEN, "chunking must cover T exactly");

using f32x4 = __attribute__((ext_vector_type(4))) float;
using s16x8 = __attribute__((ext_vector_type(8))) short;

#if __has_builtin(__builtin_amdgcn_exp2f)
#define EXP2(v) __builtin_amdgcn_exp2f(v)
#else
#define EXP2(v) exp2f(v)
#endif
#if __has_builtin(__builtin_amdgcn_rcpf)
#define RCP(v) __builtin_amdgcn_rcpf(v)
#else
#define RCP(v) (1.0f / (v))
#endif

__device__ __forceinline__ short f2bf(float f) {           // init-path only
    union { float f; unsigned u; } v; v.f = f;
    unsigned r = v.u + 0x7FFFu + ((v.u >> 16) & 1u);
    return (short)(r >> 16);
}
__device__ __forceinline__ float bf2f(short s) {
    union { unsigned u; float f; } v;
    v.u = ((unsigned)(unsigned short)s) << 16;
    return v.f;
}
__device__ __forceinline__ unsigned cvt_pk_bf16(float lo, float hi) {
    unsigned r;
    asm("v_cvt_pk_bf16_f32 %0, %1, %2" : "=v"(r) : "v"(lo), "v"(hi));
    return r;
}

// LDS-only barrier: do NOT drain vmcnt (keeps global prefetch in flight).
#define LDS_BARRIER() asm volatile("s_waitcnt lgkmcnt(0)\n\ts_barrier" ::: "memory")

__global__ __launch_bounds__(NTHREADS, 2) void lstm_fused(
    const float* __restrict__ x,    const float* __restrict__ stat,
    const float* __restrict__ h0,   const float* __restrict__ c0,
    const float* __restrict__ W_ih, const float* __restrict__ W_hh,
    const float* __restrict__ b_ih, const float* __restrict__ b_hh,
    const float* __restrict__ W_lin, const float* __restrict__ b_lin,
    float* __restrict__ out)
{
    __shared__ __align__(16) short xbuf[2][NT_CHUNK][BLK_B][XPITCH]; // 52 KiB
    __shared__ __align__(16) short hbuf[2][BLK_B][HPITCH];           // 8.5 KiB

    const int tid  = threadIdx.x;
    const int lane = tid & 63;
    const int wave = tid >> 6;
    const int lrow = lane & 15;          // A: M-row / B: N-col
    const int lk8  = (lane >> 4) << 3;   // k sub-base within a 32-wide K tile
    const int r0   = (lane >> 4) << 2;   // C/D batch-row base
    const int b0   = blockIdx.x * BLK_B;
    const int hb   = wave << 4;          // this wave's 16 hidden columns

    const float C1 = 1.44269504088896f;  // log2(e)
    const float gs[4] = { -C1, -C1, -2.0f * C1, -C1 }; // i,f,g,o pre-scales

    // ---- build weight B-fragments in registers (scale folded in) ----
    s16x8 wih[4][3], whh[4][4];
    f32x4 biasf[4];
#pragma unroll
    for (int nt = 0; nt < 4; ++nt) {
        const int col = nt * H_DIM + hb + lrow;   // gate row in W
        const float s = gs[nt];
#pragma unroll
        for (int kt = 0; kt < 3; ++kt) {
            s16x8 f;
#pragma unroll
            for (int j = 0; j < 8; ++j) {
                int k = kt * 32 + lk8 + j;
                float v = (k < F_IN) ? W_ih[col * F_IN + k] * s : 0.0f;
                f[j] = f2bf(v);
            }
            wih[nt][kt] = f;
        }
#pragma unroll
        for (int kt = 0; kt < 4; ++kt) {
            s16x8 f;
#pragma unroll
            for (int j = 0; j < 8; ++j) {
                int k = kt * 32 + lk8 + j;
                f[j] = f2bf(W_hh[col * H_DIM + k] * s);
            }
            whh[nt][kt] = f;
        }
        float bv = (b_ih[col] + b_hh[col]) * s;
        biasf[nt] = (f32x4){ bv, bv, bv, bv };
    }

    // ---- c0 into registers (C/D layout) ----
    float c[4];
#pragma unroll
    for (int r = 0; r < 4; ++r)
        c[r] = c0[(b0 + r0 + r) * H_DIM + hb + lrow];

    // ---- init hbuf[0] from h0; zero xbuf K-pad cols [76,XPITCH) ----
    for (int i = tid; i < BLK_B * H_DIM; i += NTHREADS) {
        int row = i >> 7, cc = i & 127;
        hbuf[0][row][cc] = f2bf(h0[(b0 + row) * H_DIM + cc]);
    }
    for (int i = tid; i < 2 * NT_CHUNK * BLK_B * (XPITCH - F_IN); i += NTHREADS) {
        int rem = i;
        int f   = rem % (XPITCH - F_IN); rem /= (XPITCH - F_IN);
        int row = rem % BLK_B;           rem /= BLK_B;
        int tt  = rem % NT_CHUNK;        rem /= NT_CHUNK;
        xbuf[rem][tt][row][F_IN + f] = 0;
    }

    // ---- staging: per-thread constants precomputed once ----
    const int prow = tid >> 5;            // 0..15 (batch row)
    const int pidx = tid & 31;            // f4 slot base within row-chunk
    const float* psrc = x + (size_t)(b0 + prow) * (T_LEN * F_IN) + pidx * 4;
    int ldsoff[PF_N];
#pragma unroll
    for (int i = 0; i < PF_N; ++i) {
        int s4 = pidx + 32 * i;           // f4 index in row-chunk
        int q  = 4 * s4;                  // float index
        int tp = (q * 863) >> 16;         // == q / 76 for q < 608
        int f0 = q - 76 * tp;
        ldsoff[i] = (tp * BLK_B + prow) * XPITCH + f0;  // short index in one buf
    }

    f32x4 pf[PF_N];
    auto issue = [&](int ch) {
        const float* p = psrc + (size_t)ch * (NT_CHUNK * F_IN);
#pragma unroll
        for (int i = 0; i < PF_N; ++i)
            if (i < PF_N - 1 || pidx < ROW_F4 - 4 * 32)   // s4 < 152
                pf[i] = *(const f32x4*)(p + i * 128);
    };
    auto commit = [&](int buf) {
        short* xb0 = &xbuf[buf][0][0][0];
#pragma unroll
        for (int i = 0; i < PF_N; ++i)
            if (i < PF_N - 1 || pidx < ROW_F4 - 4 * 32) {
                unsigned lo = cvt_pk_bf16(pf[i].x, pf[i].y);
                unsigned hi = cvt_pk_bf16(pf[i].z, pf[i].w);
                unsigned long long v = ((unsigned long long)hi << 32) | lo;
                *(unsigned long long*)(xb0 + ldsoff[i]) = v;  // 8B aligned
            }
    };

    issue(0);
    commit(0);
    __syncthreads();   // once; everything drained here is already consumed

    // ---- x-projection pipeline: axr0/axr1 and xa0/xa1 ping-pong regs ----
    s16x8 axr0[3], axr1[3];
    f32x4 xa0[4], xa1[4];

#define LOAD_AX(AXR, BUF, SLOT)                                                  \
    _Pragma("unroll")                                                            \
    for (int kt = 0; kt < 3; ++kt)                                               \
        AXR[kt] = *(const s16x8*)&xbuf[BUF][SLOT][lrow][kt * 32 + lk8];

#define REBUILD_ALL(XA, AXR)                                                     \
    _Pragma("unroll")                                                            \
    for (int nt = 0; nt < 4; ++nt) {                                             \
        f32x4 t = __builtin_amdgcn_mfma_f32_16x16x32_bf16(AXR[0], wih[nt][0], biasf[nt], 0, 0, 0); \
        t = __builtin_amdgcn_mfma_f32_16x16x32_bf16(AXR[1], wih[nt][1], t, 0, 0, 0); \
        t = __builtin_amdgcn_mfma_f32_16x16x32_bf16(AXR[2], wih[nt][2], t, 0, 0, 0); \
        XA[nt] = t;                                                              \
    }

#define COMBINE(R)                                                               \
    {   float p1 = 1.f + e0[R], p2 = 1.f + e1[R], p3 = 1.f + e2[R];              \
        float q13 = p1 * p3;                                                     \
        float num = fmaf(c[R], q13, (1.f - e2[R]) * p2);                         \
        float cn  = num * RCP(q13 * p2);                                         \
        c[R] = cn;                                                               \
        float Ec  = EXP2(fminf(cn * (-2.f * C1), 80.f));                         \
        hv[R] = (1.f - Ec) * RCP((1.f + e3[R]) * (1.f + Ec)); }

    // prologue for chunk 0: slot0 -> axr0 -> xa0; slot1 -> axr1 (for step0's rebuild)
    LOAD_AX(axr0, 0, 0)
    REBUILD_ALL(xa0, axr0)
    LOAD_AX(axr1, 0, 1)

    // Step t (post-barrier):
    //   1. issue ah ds_reads (critical-path LDS latency)
    //   2. REBUILD xa(t+1) from axr regs -- register-only MFMAs, no lgkm wait:
    //      fills the ds-latency hole and warms the matrix pipe
    //   3. issue axr load for slot t+2 (behind ah in the lgkm queue)
    //   4. h-MFMA (waits lgkmcnt for ah only)
    //   5. exp2 x16, combine, publish h, barrier
#define STEP(CUR, TT, XAC, XAN, AXSRC, AXDST, SLOT)                              \
    {                                                                            \
        s16x8 ah[4];                                                             \
        _Pragma("unroll")                                                        \
        for (int kt = 0; kt < 4; ++kt)                                           \
            ah[kt] = *(const s16x8*)&hbuf[CUR][lrow][kt * 32 + lk8];             \
        if ((TT) != NT_CHUNK - 1) { REBUILD_ALL(XAN, AXSRC) }                    \
        if ((TT) <= NT_CHUNK - 3) { LOAD_AX(AXDST, xc, SLOT) }                   \
        f32x4 acc[4];                                                            \
        _Pragma("unroll")                                                        \
        for (int nt = 0; nt < 4; ++nt) {                                         \
            f32x4 t = __builtin_amdgcn_mfma_f32_16x16x32_bf16(ah[0], whh[nt][0], XAC[nt], 0, 0, 0); \
            t = __builtin_amdgcn_mfma_f32_16x16x32_bf16(ah[1], whh[nt][1], t, 0, 0, 0); \
            t = __builtin_amdgcn_mfma_f32_16x16x32_bf16(ah[2], whh[nt][2], t, 0, 0, 0); \
            t = __builtin_amdgcn_mfma_f32_16x16x32_bf16(ah[3], whh[nt][3], t, 0, 0, 0); \
            acc[nt] = t;                                                         \
        }                                                                        \
        if ((TT) == 0 && ch + 1 < NCHUNK) issue(ch + 1);                         \
        float e0[4], e1[4], e2[4], e3[4];                                        \
        _Pragma("unroll")                                                        \
        for (int r = 0; r < 4; ++r) e0[r] = EXP2(acc[0][r]);                     \
        _Pragma("unroll")                                                        \
        for (int r = 0; r < 4; ++r) e1[r] = EXP2(acc[1][r]);                     \
        _Pragma("unroll")                                                        \
        for (int r = 0; r < 4; ++r) e2[r] = EXP2(acc[2][r]);                     \
        _Pragma("unroll")                                                        \
        for (int r = 0; r < 4; ++r) e3[r] = EXP2(acc[3][r]);                     \
        float hv[4];                                                             \
        unsigned short* hp = (unsigned short*)&hbuf[(CUR) ^ 1][r0][hb + lrow];   \
        COMBINE(0); COMBINE(1);                                                  \
        {   unsigned q01 = cvt_pk_bf16(hv[0], hv[1]);                            \
            hp[0 * HPITCH] = (unsigned short)q01;                                \
            hp[1 * HPITCH] = (unsigned short)(q01 >> 16); }                      \
        COMBINE(2); COMBINE(3);                                                  \
        {   unsigned q23 = cvt_pk_bf16(hv[2], hv[3]);                            \
            hp[2 * HPITCH] = (unsigned short)q23;                                \
            hp[3 * HPITCH] = (unsigned short)(q23 >> 16); }                      \
        if ((TT) == NT_CHUNK - 1 && ch + 1 < NCHUNK) commit(xc ^ 1);             \
        LDS_BARRIER();                                                           \
    }

#pragma unroll 1
    for (int ch = 0; ch < NCHUNK; ++ch) {
        const int xc = ch & 1;
        STEP(0, 0, xa0, xa1, axr1, axr0, 2)
        STEP(1, 1, xa1, xa0, axr0, axr1, 3)
        STEP(0, 2, xa0, xa1, axr1, axr0, 4)
        STEP(1, 3, xa1, xa0, axr0, axr1, 5)
        STEP(0, 4, xa0, xa1, axr1, axr0, 6)
        STEP(1, 5, xa1, xa0, axr0, axr1, 7)
        STEP(0, 6, xa0, xa1, axr1, axr0, 0)   // no load (slot arg unused)
        STEP(1, 7, xa1, xa0, axr0, axr1, 0)   // no rebuild, no load; commit pre-barrier
        // chunk boundary: fresh buffer just committed + barrier'd.
        // slot0 -> axr0 -> xa0 (for next t0); slot1 -> axr1 (for next t0's rebuild)
        if (ch + 1 < NCHUNK) {
            LOAD_AX(axr0, xc ^ 1, 0)
            REBUILD_ALL(xa0, axr0)
            LOAD_AX(axr1, xc ^ 1, 1)
        }
    }
#undef STEP
#undef COMBINE
#undef REBUILD_ALL
#undef LOAD_AX

    // ---- final linear head: out[b] = [h, static] . W_lin + b_lin ----
    // 200 steps (even) -> final h is in hbuf[0]; last LDS_BARRIER ordered it.
    if (tid < BLK_B) {
        const int row = tid;
        float a = b_lin[0];
        for (int k = 0; k < H_DIM; ++k)
            a += bf2f(hbuf[0][row][k]) * W_lin[k];
        for (int s = 0; s < S_DIM; ++s)
            a += stat[(b0 + row) * S_DIM + s] * W_lin[H_DIM + s];
        out[b0 + row] = a;
    }
}

extern "C" void kernel_launch(void* const* d_in, const int* in_sizes, int n_in,
                              void* d_out, int out_size, void* d_ws, size_t ws_size,
                              hipStream_t stream) {
    const float* xx   = (const float*)d_in[0];
    const float* st   = (const float*)d_in[1];
    const float* h0   = (const float*)d_in[2];
    const float* c0   = (const float*)d_in[3];
    const float* Wih  = (const float*)d_in[4];
    const float* Whh  = (const float*)d_in[5];
    const float* bih  = (const float*)d_in[6];
    const float* bhh  = (const float*)d_in[7];
    const float* Wlin = (const float*)d_in[8];
    const float* blin = (const float*)d_in[9];
    float* o = (float*)d_out;

    lstm_fused<<<B_TOT / BLK_B, NTHREADS, 0, stream>>>(
        xx, st, h0, c0, Wih, Whh, bih, bhh, Wlin, blin, o);
}

// Round 10
// 204.593 us; speedup vs baseline: 1.3628x; 1.0734x over previous
//
#include <hip/hip_runtime.h>
#include <hip/hip_bf16.h>

// ---- problem constants ----
#define B_TOT   4096
#define T_LEN   200
#define F_IN    76
#define H_DIM   128
#define S_DIM   17
#define BLK_B   16
#define NTHREADS 512
#define NT_CHUNK 8
#define NCHUNK  (T_LEN / NT_CHUNK)      // 25
#define XP8     144                     // bytes per x row: 128 K + 16 pad; 144=16*9 (odd p16 -> conflict-free b128)
#define XHALF8  (NT_CHUNK * BLK_B * XP8) // 18432 B per x buffer half
#define HPITCH  136                     // shorts; 272B row, p16=17 odd -> conflict-free b128
#define ROW_F4  ((NT_CHUNK * F_IN) / 4) // 152 float4 per row per chunk
#define PF_N    5

static_assert(NCHUNK * NT_CHUNK == T_LEN, "chunking must cover T exactly");

using f32x4 = __attribute__((ext_vector_type(4))) float;
using s16x8 = __attribute__((ext_vector_type(8))) short;
using i32x4 = __attribute__((ext_vector_type(4))) int;
using i32x8 = __attribute__((ext_vector_type(8))) int;

#if __has_builtin(__builtin_amdgcn_exp2f)
#define EXP2(v) __builtin_amdgcn_exp2f(v)
#else
#define EXP2(v) exp2f(v)
#endif
#if __has_builtin(__builtin_amdgcn_rcpf)
#define RCP(v) __builtin_amdgcn_rcpf(v)
#else
#define RCP(v) (1.0f / (v))
#endif

__device__ __forceinline__ short f2bf(float f) {           // init-path only
    union { float f; unsigned u; } v; v.f = f;
    unsigned r = v.u + 0x7FFFu + ((v.u >> 16) & 1u);
    return (short)(r >> 16);
}
__device__ __forceinline__ float bf2f(short s) {
    union { unsigned u; float f; } v;
    v.u = ((unsigned)(unsigned short)s) << 16;
    return v.f;
}
__device__ __forceinline__ unsigned cvt_pk_bf16(float lo, float hi) {
    unsigned r;
    asm("v_cvt_pk_bf16_f32 %0, %1, %2" : "=v"(r) : "v"(lo), "v"(hi));
    return r;
}
// pack 4 floats -> 4 fp8 e4m3 bytes (one dword)
__device__ __forceinline__ int pack_fp8x4(float a, float b, float c, float d) {
    int t = __builtin_amdgcn_cvt_pk_fp8_f32(a, b, 0, false);   // bytes 0,1
    t = __builtin_amdgcn_cvt_pk_fp8_f32(c, d, t, true);        // bytes 2,3
    return t;
}

// All-ones MX scale: every byte 127 => 2^0 for every 32-elem block.
#define MXSCALE 0x7F7F7F7F

// LDS-only barrier: do NOT drain vmcnt (keeps global prefetch in flight).
#define LDS_BARRIER() asm volatile("s_waitcnt lgkmcnt(0)\n\ts_barrier" ::: "memory")

__global__ __launch_bounds__(NTHREADS, 2) void lstm_fused(
    const float* __restrict__ x,    const float* __restrict__ stat,
    const float* __restrict__ h0,   const float* __restrict__ c0,
    const float* __restrict__ W_ih, const float* __restrict__ W_hh,
    const float* __restrict__ b_ih, const float* __restrict__ b_hh,
    const float* __restrict__ W_lin, const float* __restrict__ b_lin,
    float* __restrict__ out)
{
    __shared__ __align__(16) unsigned char xbuf8[2 * XHALF8];        // 36 KiB fp8 x
    __shared__ __align__(16) short hbuf[2][BLK_B][HPITCH];           // 8.5 KiB

    const int tid  = threadIdx.x;
    const int lane = tid & 63;
    const int wave = tid >> 6;
    const int lrow = lane & 15;          // A: M-row / B: N-col
    const int lk8  = (lane >> 4) << 3;   // bf16 k sub-base within a 32-wide K tile
    const int lk32 = (lane >> 4) << 5;   // fp8 K=128: 32 consecutive bytes per lane-quarter
    const int r0   = (lane >> 4) << 2;   // C/D batch-row base
    const int b0   = blockIdx.x * BLK_B;
    const int hb   = wave << 4;          // this wave's 16 hidden columns

    const float C1 = 1.44269504088896f;  // log2(e)
    const float gs[4] = { -C1, -C1, -2.0f * C1, -C1 }; // i,f,g,o pre-scales

    // ---- weight fragments in registers (scale folded in) ----
    s16x8 whh[4][4];       // h-GEMM stays bf16 (recurrent path needs precision)
    i32x8 wih8[4];         // x-proj B-frags in fp8 e4m3, K=128 (76 real + 0 pad)
    f32x4 biasf[4];
#pragma unroll
    for (int nt = 0; nt < 4; ++nt) {
        const int col = nt * H_DIM + hb + lrow;   // gate row in W
        const float s = gs[nt];
#pragma unroll
        for (int kt = 0; kt < 4; ++kt) {
            s16x8 f;
#pragma unroll
            for (int j = 0; j < 8; ++j) {
                int k = kt * 32 + lk8 + j;
                f[j] = f2bf(W_hh[col * H_DIM + k] * s);
            }
            whh[nt][kt] = f;
        }
        i32x8 g;
#pragma unroll
        for (int d = 0; d < 8; ++d) {
            float v[4];
#pragma unroll
            for (int e = 0; e < 4; ++e) {
                int k = lk32 + 4 * d + e;
                v[e] = (k < F_IN) ? W_ih[col * F_IN + k] * s : 0.0f;
            }
            g[d] = pack_fp8x4(v[0], v[1], v[2], v[3]);
        }
        wih8[nt] = g;
        float bv = (b_ih[col] + b_hh[col]) * s;
        biasf[nt] = (f32x4){ bv, bv, bv, bv };
    }

    // ---- c0 into registers (C/D layout) ----
    float c[4];
#pragma unroll
    for (int r = 0; r < 4; ++r)
        c[r] = c0[(b0 + r0 + r) * H_DIM + hb + lrow];

    // ---- init hbuf[0] from h0; zero xbuf8 pad bytes [76,XP8) per row ----
    for (int i = tid; i < BLK_B * H_DIM; i += NTHREADS) {
        int row = i >> 7, cc = i & 127;
        hbuf[0][row][cc] = f2bf(h0[(b0 + row) * H_DIM + cc]);
    }
    for (int i = tid; i < 2 * NT_CHUNK * BLK_B * (XP8 - F_IN); i += NTHREADS) {
        int f  = i % (XP8 - F_IN);
        int rs = i / (XP8 - F_IN);
        xbuf8[rs * XP8 + F_IN + f] = 0;
    }

    // ---- staging: per-thread constants precomputed once ----
    const int prow = tid >> 5;            // 0..15 (batch row)
    const int pidx = tid & 31;            // f4 slot base within row-chunk
    const float* psrc = x + (size_t)(b0 + prow) * (T_LEN * F_IN) + pidx * 4;
    int ldsoff[PF_N];
#pragma unroll
    for (int i = 0; i < PF_N; ++i) {
        int s4 = pidx + 32 * i;           // f4 index in row-chunk
        int q  = 4 * s4;                  // float index == byte index in fp8 row
        int tp = (q * 863) >> 16;         // == q / 76 for q < 608
        int f0 = q - 76 * tp;             // multiple of 4
        ldsoff[i] = (tp * BLK_B + prow) * XP8 + f0;  // byte offset in one buf
    }

    f32x4 pf[PF_N];
    auto issue = [&](int ch) {
        const float* p = psrc + (size_t)ch * (NT_CHUNK * F_IN);
#pragma unroll
        for (int i = 0; i < PF_N; ++i)
            if (i < PF_N - 1 || pidx < ROW_F4 - 4 * 32)   // s4 < 152
                pf[i] = *(const f32x4*)(p + i * 128);
    };
    auto commit = [&](int buf) {
        unsigned char* xb0 = xbuf8 + buf * XHALF8;
#pragma unroll
        for (int i = 0; i < PF_N; ++i)
            if (i < PF_N - 1 || pidx < ROW_F4 - 4 * 32)
                *(int*)(xb0 + ldsoff[i]) = pack_fp8x4(pf[i].x, pf[i].y, pf[i].z, pf[i].w);
    };

    issue(0);
    commit(0);
    __syncthreads();   // once; everything drained here is already consumed

    // ---- x-projection: one MX-scaled K=128 MFMA per gate tile ----
    i32x8 ax8;
    f32x4 xa[4];
    auto load_ax = [&](int buf, int tt) {
        const unsigned char* bp = xbuf8 + buf * XHALF8
                                + (tt * BLK_B + lrow) * XP8 + lk32;
        i32x4 lo = *(const i32x4*)bp;
        i32x4 hi = *(const i32x4*)(bp + 16);
        ax8[0] = lo[0]; ax8[1] = lo[1]; ax8[2] = lo[2]; ax8[3] = lo[3];
        ax8[4] = hi[0]; ax8[5] = hi[1]; ax8[6] = hi[2]; ax8[7] = hi[3];
    };

#define REBUILD(NT)                                                              \
    xa[NT] = __builtin_amdgcn_mfma_scale_f32_16x16x128_f8f6f4(                   \
        ax8, wih8[NT], biasf[NT], 0, 0, 0, MXSCALE, 0, MXSCALE);

#define COMBINE(R)                                                               \
    {   float p1 = 1.f + e0[R], p2 = 1.f + e1[R], p3 = 1.f + e2[R];              \
        float q13 = p1 * p3;                                                     \
        float num = fmaf(c[R], q13, (1.f - e2[R]) * p2);                         \
        float cn  = num * RCP(q13 * p2);                                         \
        c[R] = cn;                                                               \
        float Ec  = EXP2(fminf(cn * (-2.f * C1), 80.f));                         \
        hv[R] = (1.f - Ec) * RCP((1.f + e3[R]) * (1.f + Ec)); }

    // prologue for chunk 0, step 0
    load_ax(0, 0);
    REBUILD(0) REBUILD(1) REBUILD(2) REBUILD(3)

#define STEP(CUR, TT)                                                            \
    {                                                                            \
        s16x8 ah[4];                                                             \
        _Pragma("unroll")                                                        \
        for (int kt = 0; kt < 4; ++kt)                                           \
            ah[kt] = *(const s16x8*)&hbuf[CUR][lrow][kt * 32 + lk8];             \
        if ((TT) < NT_CHUNK - 1) load_ax(xc, (TT) + 1);                          \
        f32x4 acc[4];                                                            \
        _Pragma("unroll")                                                        \
        for (int nt = 0; nt < 4; ++nt) {                                         \
            f32x4 t = __builtin_amdgcn_mfma_f32_16x16x32_bf16(ah[0], whh[nt][0], xa[nt], 0, 0, 0); \
            t = __builtin_amdgcn_mfma_f32_16x16x32_bf16(ah[1], whh[nt][1], t, 0, 0, 0); \
            t = __builtin_amdgcn_mfma_f32_16x16x32_bf16(ah[2], whh[nt][2], t, 0, 0, 0); \
            t = __builtin_amdgcn_mfma_f32_16x16x32_bf16(ah[3], whh[nt][3], t, 0, 0, 0); \
            acc[nt] = t;                                                         \
        }                                                                        \
        if ((TT) == 0 && ch + 1 < NCHUNK) issue(ch + 1);                         \
        float e0[4], e1[4], e2[4], e3[4];                                        \
        _Pragma("unroll")                                                        \
        for (int r = 0; r < 4; ++r) e0[r] = EXP2(acc[0][r]);                     \
        _Pragma("unroll")                                                        \
        for (int r = 0; r < 4; ++r) e1[r] = EXP2(acc[1][r]);                     \
        _Pragma("unroll")                                                        \
        for (int r = 0; r < 4; ++r) e2[r] = EXP2(acc[2][r]);                     \
        _Pragma("unroll")                                                        \
        for (int r = 0; r < 4; ++r) e3[r] = EXP2(acc[3][r]);                     \
        if ((TT) < NT_CHUNK - 1) { REBUILD(0) REBUILD(1) REBUILD(2) REBUILD(3) } \
        float hv[4];                                                             \
        unsigned short* hp = (unsigned short*)&hbuf[(CUR) ^ 1][r0][hb + lrow];   \
        COMBINE(0); COMBINE(1);                                                  \
        {   unsigned q01 = cvt_pk_bf16(hv[0], hv[1]);                            \
            hp[0 * HPITCH] = (unsigned short)q01;                                \
            hp[1 * HPITCH] = (unsigned short)(q01 >> 16); }                      \
        COMBINE(2); COMBINE(3);                                                  \
        {   unsigned q23 = cvt_pk_bf16(hv[2], hv[3]);                            \
            hp[2 * HPITCH] = (unsigned short)q23;                                \
            hp[3 * HPITCH] = (unsigned short)(q23 >> 16); }                      \
        if ((TT) == NT_CHUNK - 1 && ch + 1 < NCHUNK) commit(xc ^ 1);             \
        LDS_BARRIER();                                                           \
    }

#pragma unroll 1
    for (int ch = 0; ch < NCHUNK; ++ch) {
        const int xc = ch & 1;
        STEP(0, 0)
        STEP(1, 1)
        STEP(0, 2)
        STEP(1, 3)
        STEP(0, 4)
        STEP(1, 5)
        STEP(0, 6)
        STEP(1, 7)
        // chunk boundary: x-projection for (ch+1, tt=0) from fresh buffer
        if (ch + 1 < NCHUNK) {
            load_ax(xc ^ 1, 0);
            REBUILD(0) REBUILD(1) REBUILD(2) REBUILD(3)
        }
    }
#undef STEP
#undef COMBINE
#undef REBUILD

    // ---- final linear head: out[b] = [h, static] . W_lin + b_lin ----
    // 200 steps (even) -> final h is in hbuf[0]; last LDS_BARRIER ordered it.
    if (tid < BLK_B) {
        const int row = tid;
        float a = b_lin[0];
        for (int k = 0; k < H_DIM; ++k)
            a += bf2f(hbuf[0][row][k]) * W_lin[k];
        for (int s = 0; s < S_DIM; ++s)
            a += stat[(b0 + row) * S_DIM + s] * W_lin[H_DIM + s];
        out[b0 + row] = a;
    }
}

extern "C" void kernel_launch(void* const* d_in, const int* in_sizes, int n_in,
                              void* d_out, int out_size, void* d_ws, size_t ws_size,
                              hipStream_t stream) {
    const float* xx   = (const float*)d_in[0];
    const float* st   = (const float*)d_in[1];
    const float* h0   = (const float*)d_in[2];
    const float* c0   = (const float*)d_in[3];
    const float* Wih  = (const float*)d_in[4];
    const float* Whh  = (const float*)d_in[5];
    const float* bih  = (const float*)d_in[6];
    const float* bhh  = (const float*)d_in[7];
    const float* Wlin = (const float*)d_in[8];
    const float* blin = (const float*)d_in[9];
    float* o = (float*)d_out;

    lstm_fused<<<B_TOT / BLK_B, NTHREADS, 0, stream>>>(
        xx, st, h0, c0, Wih, Whh, bih, bhh, Wlin, blin, o);
}